// Round 13
// baseline (204.359 us; speedup 1.0000x reference)
//
#include <hip/hip_runtime.h>
#include <math.h>

#define SLEN 2048
#define BATCH 8
#define DMODEL 256
#define HEADS 8
#define DPROJ 128
#define DFF 1024
#define DH 16
#define MROWS (SLEN*BATCH)   // 16384

typedef unsigned short u16;
typedef unsigned int u32;
typedef __attribute__((ext_vector_type(8))) short short8;
typedef __attribute__((ext_vector_type(4))) float f32x4;
typedef __attribute__((ext_vector_type(4))) unsigned short u16x4;

__device__ __forceinline__ u16 f2bf(float x) {
    union { float f; u32 u; } v; v.f = x;
    u32 r = v.u + 0x7FFFu + ((v.u >> 16) & 1u);
    return (u16)(r >> 16);
}
__device__ __forceinline__ float bf2f(u16 h) {
    union { u32 u; float f; } v; v.u = ((u32)h) << 16;
    return v.f;
}
__device__ __forceinline__ float fexp2(float x) { return __builtin_amdgcn_exp2f(x); }
// pack bf16(lo),bf16(hi) (truncating) into one dword via v_perm_b32; the
// truncation bias cancels in O/L since L is computed from the same truncated P
__device__ __forceinline__ u32 pack_bf(float lo, float hi) {
    union { float f; u32 u; } a, b; a.f = lo; b.f = hi;
    return __builtin_amdgcn_perm(b.u, a.u, 0x07060302u);
}
// async global->LDS 16B: per-lane global addr, wave-uniform LDS base
// (HW writes lds_base + lane*16)
__device__ __forceinline__ void gld16(const u16* g, u16* l) {
    __builtin_amdgcn_global_load_lds(
        (const __attribute__((address_space(1))) void*)g,
        (__attribute__((address_space(3))) void*)l, 16, 0, 0);
}

// ---------------------------------------------------------------------------
// prep: src fp32->bf16 (blocks 0..4095) + weight transpose+convert (rest)
// ---------------------------------------------------------------------------
__global__ void prep_kernel(const float* __restrict__ src, u16* __restrict__ srcb,
                            const float* __restrict__ Wq, const float* __restrict__ Wk,
                            const float* __restrict__ Wv, const float* __restrict__ Wo,
                            const float* __restrict__ W1, const float* __restrict__ W2,
                            u16* __restrict__ WqT, u16* __restrict__ WkT,
                            u16* __restrict__ WvT, u16* __restrict__ WoT,
                            u16* __restrict__ W1T, u16* __restrict__ W2T) {
    if (blockIdx.x < 4096) {
        int idx = (blockIdx.x * 256 + threadIdx.x) * 4;
        float4 v = *(const float4*)(src + idx);
        u16x4 o;
        o.x = f2bf(v.x); o.y = f2bf(v.y); o.z = f2bf(v.z); o.w = f2bf(v.w);
        *(u16x4*)(srcb + idx) = o;
        return;
    }
    int i = (blockIdx.x - 4096) * 256 + threadIdx.x;
    if (i < 32768) {                       // WqT [128][256]
        int n = i >> 8, k = i & 255;
        WqT[i] = f2bf(Wq[k * 128 + n]);
    } else if (i < 65536) {
        int j = i - 32768; int n = j >> 8, k = j & 255;
        WkT[j] = f2bf(Wk[k * 128 + n]);
    } else if (i < 98304) {
        int j = i - 65536; int n = j >> 8, k = j & 255;
        WvT[j] = f2bf(Wv[k * 128 + n]);
    } else if (i < 131072) {               // WoT [256][128]
        int j = i - 98304; int n = j >> 7, k = j & 127;
        WoT[j] = f2bf(Wo[k * 256 + n]);
    } else if (i < 393216) {               // W1T [1024][256]
        int j = i - 131072; int n = j >> 8, k = j & 255;
        W1T[j] = f2bf(W1[k * 1024 + n]);
    } else if (i < 655360) {               // W2T [256][1024]
        int j = i - 393216; int n = j >> 10, k = j & 1023;
        W2T[j] = f2bf(W2[k * 256 + n]);
    }
}

// ---------------------------------------------------------------------------
// bf16 MFMA GEMM v2 — double-buffered LDS, ONE barrier per 32-K step.
// (unchanged; used for FFN1 — pairing K-steps here would halve its
//  4 blocks/CU occupancy per the m132 regression, so it stays single.)
// ---------------------------------------------------------------------------
template<int BM, int BN, bool RELU, bool HAS_BIAS, bool OUT_BF16>
__global__ void mfma_gemm(const u16* __restrict__ A, const u16* __restrict__ BT,
                          const float* __restrict__ bias, void* __restrict__ Cout,
                          int M, int N, int K) {
    constexpr int MI = BM / 32;
    constexpr int NJ = BN / 32;
    __shared__ __align__(16) u16 As[2][BM * 32];
    __shared__ __align__(16) u16 Bs[2][BN * 32];
    const int tid = threadIdx.x;
    const int row0 = blockIdx.x * BM;
    const int col0 = blockIdx.y * BN;
    const int w = tid >> 6, l = tid & 63;
    const int wr = (w & 1) * (BM / 2), wc = (w >> 1) * (BN / 2);
    const int lcol = l & 15, lrow = (l >> 4) * 4, g = l >> 4;
    const int sl = l >> 2;                       // sub-row within 16-row band
    const int swc = ((l & 3) ^ (sl & 3)) * 8;    // swizzled global chunk (u16)
    const int fsw = (g ^ (lcol & 3)) * 8;        // fragment slot offset (u16)

    const u16* Ag0 = A + (size_t)(row0 + 16 * w + sl) * K + swc;
    const u16* Bg0 = BT + (size_t)(col0 + 16 * w + sl) * K + swc;
    const int lofs = (16 * w) * 32;              // wave's staging band (u16)

    f32x4 acc[MI][NJ] = {};
    // prologue: stage k=0 into buffer 0
    gld16(Ag0, As[0] + lofs);
    if (BM == 128) gld16(Ag0 + (size_t)64 * K, As[0] + lofs + 64 * 32);
    gld16(Bg0, Bs[0] + lofs);
    if (BN == 128) gld16(Bg0 + (size_t)64 * K, Bs[0] + lofs + 64 * 32);
    __syncthreads();

    int cur = 0;
    for (int k0 = 0; k0 < K; k0 += 32) {
        // stage next 32-K slice into the other buffer (lands at the barrier)
        if (k0 + 32 < K) {
            const int nb = cur ^ 1;
            gld16(Ag0 + k0 + 32, As[nb] + lofs);
            if (BM == 128) gld16(Ag0 + (size_t)64 * K + k0 + 32, As[nb] + lofs + 64 * 32);
            gld16(Bg0 + k0 + 32, Bs[nb] + lofs);
            if (BN == 128) gld16(Bg0 + (size_t)64 * K + k0 + 32, Bs[nb] + lofs + 64 * 32);
        }
        short8 af[MI], bf[NJ];
        #pragma unroll
        for (int i = 0; i < MI; ++i)
            af[i] = *(const short8*)(As[cur] + (wr + i * 16 + lcol) * 32 + fsw);
        #pragma unroll
        for (int j = 0; j < NJ; ++j)
            bf[j] = *(const short8*)(Bs[cur] + (wc + j * 16 + lcol) * 32 + fsw);
        #pragma unroll
        for (int i = 0; i < MI; ++i)
            #pragma unroll
            for (int j = 0; j < NJ; ++j)
                acc[i][j] = __builtin_amdgcn_mfma_f32_16x16x32_bf16(
                    af[i], bf[j], acc[i][j], 0, 0, 0);
        __syncthreads();
        cur ^= 1;
    }
    float bv[NJ];
    #pragma unroll
    for (int j = 0; j < NJ; ++j)
        bv[j] = HAS_BIAS ? bias[col0 + wc + j * 16 + lcol] : 0.f;
    #pragma unroll
    for (int i = 0; i < MI; ++i) {
        #pragma unroll
        for (int r = 0; r < 4; ++r) {
            size_t grow = row0 + wr + i * 16 + lrow + r;
            #pragma unroll
            for (int j = 0; j < NJ; ++j) {
                int gcol = col0 + wc + j * 16 + lcol;
                float c = acc[i][j][r] + bv[j];
                if (RELU) c = fmaxf(c, 0.f);
                if (OUT_BF16) ((u16*)Cout)[grow * N + gcol] = f2bf(c);
                else          ((float*)Cout)[grow * N + gcol] = c;
            }
        }
    }
}

// ---------------------------------------------------------------------------
// Fused GEMM + residual-add + LayerNorm, TWO 32-K slices per barrier
// interval (round-6 attn pattern). Grid 512 = 2 blocks/CU is grid-limited,
// so the 72.5 KB LDS costs no occupancy. Wo: 4->2 intervals; FFN2: 32->16.
// Full-width tile 32 x 256; in-block LN via 16-lane butterfly + 512B LDS.
// ---------------------------------------------------------------------------
template<bool HAS_BIAS, bool RESID_F32, bool OUT_BF16>
__global__ void gemm_ln(const u16* __restrict__ A, const u16* __restrict__ BT,
                        const float* __restrict__ bias,
                        const void* __restrict__ resid,
                        const float* __restrict__ lng, const float* __restrict__ lnb,
                        void* __restrict__ Cout, int K) {
    __shared__ __align__(16) u16 As[2][2][32 * 32];   //  8 KB [buf][slice]
    __shared__ __align__(16) u16 Bs[2][2][256 * 32];  // 64 KB
    __shared__ float Ls[2][32][2];                    // 512 B
    const int tid = threadIdx.x;
    const int row0 = blockIdx.x * 32;
    const int w = tid >> 6, l = tid & 63;
    const int wr = (w & 1) * 16, wc = (w >> 1) * 128;
    const int lcol = l & 15, lrow = (l >> 4) * 4, g = l >> 4;
    const int sl = l >> 2;
    const int swc = ((l & 3) ^ (sl & 3)) * 8;
    const int fsw = (g ^ (lcol & 3)) * 8;

    u16* AsF = (u16*)As;   // buf stride 2048 u16, slice stride 1024
    u16* BsF = (u16*)Bs;   // buf stride 16384 u16, slice stride 8192

    // A staging: waves 0,1 stage 16-row band (w&1); waves 2,3 skip A
    const u16* Ag = A + (size_t)(row0 + 16 * (w & 1) + sl) * K + swc;
    const int lA0 = (16 * (w & 1)) * 32;
    // B staging: wave w stages bands w, w+4, w+8, w+12 (4 x 1KB per slice)
    const u16* Bg[4];
    int lB0[4];
    #pragma unroll
    for (int t = 0; t < 4; ++t) {
        Bg[t] = BT + (size_t)(16 * (w + 4 * t) + sl) * K + swc;
        lB0[t] = (16 * (w + 4 * t)) * 32;
    }

    f32x4 acc[8] = {};
    // prologue: stage interval 0 (slices k=0, k=32) into buffer 0
    if (w < 2) { gld16(Ag, AsF + lA0); gld16(Ag + 32, AsF + 1024 + lA0); }
    #pragma unroll
    for (int t = 0; t < 4; ++t) {
        gld16(Bg[t], BsF + lB0[t]);
        gld16(Bg[t] + 32, BsF + 8192 + lB0[t]);
    }
    __syncthreads();

    int cur = 0;
    for (int k0 = 0; k0 < K; k0 += 64) {
        // stage next interval (both slices) into the other buffer
        if (k0 + 64 < K) {
            const int nb = cur ^ 1;
            const int kn = k0 + 64;
            if (w < 2) {
                gld16(Ag + kn,      AsF + nb * 2048 + lA0);
                gld16(Ag + kn + 32, AsF + nb * 2048 + 1024 + lA0);
            }
            #pragma unroll
            for (int t = 0; t < 4; ++t) {
                gld16(Bg[t] + kn,      BsF + nb * 16384 + lB0[t]);
                gld16(Bg[t] + kn + 32, BsF + nb * 16384 + 8192 + lB0[t]);
            }
        }
        #pragma unroll
        for (int s2 = 0; s2 < 2; ++s2) {
            const u16* Ac = AsF + cur * 2048 + s2 * 1024;
            const u16* Bc = BsF + cur * 16384 + s2 * 8192;
            short8 af = *(const short8*)(Ac + (wr + lcol) * 32 + fsw);
            short8 bf[8];
            #pragma unroll
            for (int j = 0; j < 8; ++j)
                bf[j] = *(const short8*)(Bc + (wc + j * 16 + lcol) * 32 + fsw);
            #pragma unroll
            for (int j = 0; j < 8; ++j)
                acc[j] = __builtin_amdgcn_mfma_f32_16x16x32_bf16(af, bf[j], acc[j], 0, 0, 0);
        }
        __syncthreads();
        cur ^= 1;
    }

    // epilogue: e = acc + bias + resid  (acc[j][r] -> row wr+lrow+r, col wc+j*16+lcol)
    #pragma unroll
    for (int j = 0; j < 8; ++j) {
        const int col = wc + j * 16 + lcol;
        const float bv = HAS_BIAS ? bias[col] : 0.f;
        #pragma unroll
        for (int r = 0; r < 4; ++r) {
            const size_t row = (size_t)row0 + wr + lrow + r;
            float rv;
            if (RESID_F32) rv = ((const float*)resid)[row * 256 + col];
            else           rv = bf2f(((const u16*)resid)[row * 256 + col]);
            acc[j][r] += bv + rv;
        }
    }
    // per-row partials over this thread's 8 cols
    float s[4] = {0.f, 0.f, 0.f, 0.f}, q[4] = {0.f, 0.f, 0.f, 0.f};
    #pragma unroll
    for (int j = 0; j < 8; ++j)
        #pragma unroll
        for (int r = 0; r < 4; ++r) { s[r] += acc[j][r]; q[r] += acc[j][r] * acc[j][r]; }
    // butterfly over the 16-lane group sharing these rows (covers wave's 128 cols)
    #pragma unroll
    for (int off = 1; off < 16; off <<= 1)
        #pragma unroll
        for (int r = 0; r < 4; ++r) { s[r] += __shfl_xor(s[r], off); q[r] += __shfl_xor(q[r], off); }
    if (lcol == 0)
        #pragma unroll
        for (int r = 0; r < 4; ++r) {
            Ls[w >> 1][wr + lrow + r][0] = s[r];
            Ls[w >> 1][wr + lrow + r][1] = q[r];
        }
    __syncthreads();
    float mu[4], rs[4];
    #pragma unroll
    for (int r = 0; r < 4; ++r) {
        const int row = wr + lrow + r;
        const float fs = Ls[0][row][0] + Ls[1][row][0];
        const float fq = Ls[0][row][1] + Ls[1][row][1];
        mu[r] = fs * (1.0f / 256.0f);
        const float var = fq * (1.0f / 256.0f) - mu[r] * mu[r];
        rs[r] = rsqrtf(var + 1e-5f);
    }
    #pragma unroll
    for (int j = 0; j < 8; ++j) {
        const int col = wc + j * 16 + lcol;
        const float gv = lng[col], b2v = lnb[col];
        #pragma unroll
        for (int r = 0; r < 4; ++r) {
            const size_t row = (size_t)row0 + wr + lrow + r;
            const float o = (acc[j][r] - mu[r]) * rs[r] * gv + b2v;
            if (OUT_BF16) ((u16*)Cout)[row * 256 + col] = f2bf(o);
            else          ((float*)Cout)[row * 256 + col] = o;
        }
    }
}

// ---------------------------------------------------------------------------
// QKV MFMA GEMM v4 — TWO 32-K slices per barrier interval (8 -> 4
// intervals). Grid 384 = 1.5 blocks/CU is grid-limited, so the 64 KB LDS
// costs no occupancy. Outputs (coalesced vector stores, round-9 form):
//   q -> qhp [bh][s][32], scaled 0.25*log2e, dh 16..31 zero
//   k -> khp [bh][s][32], dh 16..31 zero
//   v -> vhb [bh][s][16]   (transposed by the separate transpose_v kernel —
//        round 10 measured the fused scatter at +7.5us, so it stays split)
// ---------------------------------------------------------------------------
__global__ void qkv_mfma(const u16* __restrict__ A,
                         const u16* __restrict__ WqT, const u16* __restrict__ WkT,
                         const u16* __restrict__ WvT,
                         const float* __restrict__ bq, const float* __restrict__ bk,
                         const float* __restrict__ bv,
                         u16* __restrict__ qhp, u16* __restrict__ khp,
                         u16* __restrict__ vhb) {
    const int which = blockIdx.z;
    const u16* BT   = which == 0 ? WqT : (which == 1 ? WkT : WvT);
    const float* bs = which == 0 ? bq : (which == 1 ? bk : bv);
    const float scale = which == 0 ? 0.25f * 1.44269504f : 1.0f;
    __shared__ __align__(16) u16 As[2][2][128 * 32];  // 32 KB [buf][slice]
    __shared__ __align__(16) u16 Bs[2][2][128 * 32];  // 32 KB
    const int tid = threadIdx.x;
    const int row0 = blockIdx.x * 128;
    const int w = tid >> 6, l = tid & 63;
    const int wr = (w & 1) * 64, wc = (w >> 1) * 64;
    const int lcol = l & 15, lrow = (l >> 4) * 4, g = l >> 4;
    const int sl = l >> 2;
    const int swc = ((l & 3) ^ (sl & 3)) * 8;
    const int fsw = (g ^ (lcol & 3)) * 8;

    u16* AsF = (u16*)As;   // buf stride 8192 u16, slice stride 4096
    u16* BsF = (u16*)Bs;
    const u16* Ag0 = A + (size_t)(row0 + 16 * w + sl) * DMODEL + swc;
    const u16* Bg0 = BT + (size_t)(16 * w + sl) * DMODEL + swc;
    const int lofs = (16 * w) * 32;

    f32x4 acc[4][4] = {};
    // prologue: stage interval 0 (slices k=0, k=32) into buffer 0
    gld16(Ag0,                       AsF + lofs);
    gld16(Ag0 + (size_t)64 * DMODEL, AsF + lofs + 2048);
    gld16(Ag0 + 32,                       AsF + 4096 + lofs);
    gld16(Ag0 + (size_t)64 * DMODEL + 32, AsF + 4096 + lofs + 2048);
    gld16(Bg0,                       BsF + lofs);
    gld16(Bg0 + (size_t)64 * DMODEL, BsF + lofs + 2048);
    gld16(Bg0 + 32,                       BsF + 4096 + lofs);
    gld16(Bg0 + (size_t)64 * DMODEL + 32, BsF + 4096 + lofs + 2048);
    __syncthreads();

    int cur = 0;
    for (int k0 = 0; k0 < DMODEL; k0 += 64) {
        if (k0 + 64 < DMODEL) {
            const int nb = cur ^ 1;
            const int kn = k0 + 64;
            gld16(Ag0 + kn,                       AsF + nb * 8192 + lofs);
            gld16(Ag0 + (size_t)64 * DMODEL + kn, AsF + nb * 8192 + lofs + 2048);
            gld16(Ag0 + kn + 32,                       AsF + nb * 8192 + 4096 + lofs);
            gld16(Ag0 + (size_t)64 * DMODEL + kn + 32, AsF + nb * 8192 + 4096 + lofs + 2048);
            gld16(Bg0 + kn,                       BsF + nb * 8192 + lofs);
            gld16(Bg0 + (size_t)64 * DMODEL + kn, BsF + nb * 8192 + lofs + 2048);
            gld16(Bg0 + kn + 32,                       BsF + nb * 8192 + 4096 + lofs);
            gld16(Bg0 + (size_t)64 * DMODEL + kn + 32, BsF + nb * 8192 + 4096 + lofs + 2048);
        }
        #pragma unroll
        for (int s2 = 0; s2 < 2; ++s2) {
            const u16* Ac = AsF + cur * 8192 + s2 * 4096;
            const u16* Bc = BsF + cur * 8192 + s2 * 4096;
            short8 af[4], bf[4];
            #pragma unroll
            for (int i = 0; i < 4; ++i)
                af[i] = *(const short8*)(Ac + (wr + i * 16 + lcol) * 32 + fsw);
            #pragma unroll
            for (int j = 0; j < 4; ++j)
                bf[j] = *(const short8*)(Bc + (wc + j * 16 + lcol) * 32 + fsw);
            #pragma unroll
            for (int i = 0; i < 4; ++i)
                #pragma unroll
                for (int j = 0; j < 4; ++j)
                    acc[i][j] = __builtin_amdgcn_mfma_f32_16x16x32_bf16(
                        af[i], bf[j], acc[i][j], 0, 0, 0);
        }
        __syncthreads();
        cur ^= 1;
    }
    #pragma unroll
    for (int i = 0; i < 4; ++i) {
        #pragma unroll
        for (int r = 0; r < 4; ++r) {
            int grow = row0 + wr + i * 16 + lrow + r;
            int b = grow & 7, s = grow >> 3;
            #pragma unroll
            for (int j = 0; j < 4; ++j) {
                int gcol = wc + j * 16 + lcol;
                int h = gcol >> 4, d = gcol & 15;
                float c = acc[i][j][r] + bs[gcol];
                if (which == 2) {
                    vhb[((size_t)(b * 8 + h) * SLEN + s) * 16 + d] = f2bf(c);
                } else {
                    u16* base = (which == 0 ? qhp : khp)
                              + ((size_t)(b * 8 + h) * SLEN + s) * 32;
                    base[d] = f2bf(c * scale);
                    base[d + 16] = 0;
                }
            }
        }
    }
}

// ---------------------------------------------------------------------------
// V transpose: vhb [bh][s][16] -> vT [bh][dh][2048]
// ---------------------------------------------------------------------------
__global__ void transpose_v(const u16* __restrict__ vhb, u16* __restrict__ vT) {
    __shared__ u16 T[128 * 24];
    const int bh = blockIdx.y;
    const int c0 = blockIdx.x * 128;
    const int t = threadIdx.x;
    {
        int key = t >> 1, half = t & 1;
        *(uint4*)(T + key * 24 + half * 8) =
            *(const uint4*)(vhb + ((size_t)bh * SLEN + c0 + key) * 16 + half * 8);
    }
    __syncthreads();
    int d = t >> 4, k8 = (t & 15) * 8;
    u16x4 o0, o1;
    o0.x = T[(k8 + 0) * 24 + d]; o0.y = T[(k8 + 1) * 24 + d];
    o0.z = T[(k8 + 2) * 24 + d]; o0.w = T[(k8 + 3) * 24 + d];
    o1.x = T[(k8 + 4) * 24 + d]; o1.y = T[(k8 + 5) * 24 + d];
    o1.z = T[(k8 + 6) * 24 + d]; o1.w = T[(k8 + 7) * 24 + d];
    u16* dst = vT + ((size_t)bh * 16 + d) * SLEN + c0 + k8;
    *(u16x4*)dst = o0;
    *(u16x4*)(dst + 4) = o1;
}

// ---------------------------------------------------------------------------
// MFMA flash attention v11 — THREE 64-key tiles per barrier interval.
// Interval schedule [2, 3x10]: 11 barriers (was 16). LDS = 2 bufs x 3 tiles
// x (4KB K + 2KB V) = 36864 B -> still 4 blocks/CU (160/36 = 4.4), unlike
// 4-tile pairing (48KB -> 3 blocks/CU, tail risk on the exactly-4/CU grid).
// Body unchanged from v10 (register-P, permuted-key V fragments).
// ---------------------------------------------------------------------------
__global__ __launch_bounds__(256, 4)
void attn_mfma(const u16* __restrict__ qg, const u16* __restrict__ kg,
               const u16* __restrict__ vT, u16* __restrict__ ctx) {
    __shared__ __align__(16) u16 Ks[2][3][64 * 32];   // 24576 B [buf][slot]
    __shared__ __align__(16) u16 Vs[2][3][16 * 64];   // 12288 B [buf][slot]
    const int bh = blockIdx.y;
    const int q0 = blockIdx.x * 128;
    const int tid = threadIdx.x;
    const int w = tid >> 6, l = tid & 63;
    const int qc = l & 15, g = l >> 4;

    // Q fragments: 32 rows per wave, loaded once
    short8 qf[2];
    {
        const u16* qbase = qg + ((size_t)bh * SLEN + q0 + w * 32) * 32;
        qf[0] = *(const short8*)(qbase + qc * 32 + 8 * g);
        qf[1] = *(const short8*)(qbase + (16 + qc) * 32 + 8 * g);
    }

    // K staging: wave w stages 16-row band w of each 64-key tile (1 gld16).
    const int sl = l >> 2;
    const int swc = ((l & 3) ^ (sl & 3)) * 8;
    const u16* Kg = kg + (size_t)bh * SLEN * 32 + (size_t)(16 * w + sl) * 32 + swc;
    u16* KsF = (u16*)Ks;                 // buf stride 6144 u16, slot stride 2048
    const int kband = (16 * w) * 32;
    // V staging: tile = 16 dh-rows x 64 keys; w==0 stages rows 0-7, w==1
    // rows 8-15; chunk slot c holds global chunk c^(row&7).
    const int vr = l >> 3, vc = l & 7;
    const int vsw0 = (vc ^ (vr & 7)) * 8;
    const u16* Vg0 = vT + ((size_t)bh * 16 + vr) * SLEN + vsw0;      // rows 0-7
    const u16* Vg1 = vT + ((size_t)bh * 16 + 8 + vr) * SLEN + vsw0;  // rows 8-15
    u16* VsF = (u16*)Vs;                 // buf stride 3072 u16, slot stride 1024
    // fragment offsets
    const int fsw = (g ^ (qc & 3)) * 8;            // K: [row][32] pattern
    const int qx = qc & 7, gh = g >> 1, gs = (g & 1) * 4;
    const int vrow = qc * 64;                      // V row base (u16)

    f32x4 o_[2] = {};
    f32x4 ls[2] = {};
    const short one_bf = (short)0x3F80;
    short8 onesB = {one_bf, one_bf, one_bf, one_bf, one_bf, one_bf, one_bf, one_bf};

    // one-tile compute body (register-P, permuted-key V fragments)
    auto compute_tile = [&](const u16* Kc, const u16* Vc) {
        short8 kf[4];
        #pragma unroll
        for (int kj = 0; kj < 4; ++kj)
            kf[kj] = *(const short8*)(Kc + (kj * 16 + qc) * 32 + fsw);
        short8 vfrag[2];
        #pragma unroll
        for (int ks = 0; ks < 2; ++ks) {
            union { u32 d[4]; short8 v; } vv;
            uint2 va = *(const uint2*)(Vc + vrow + ((4 * ks + gh) ^ qx) * 8 + gs);
            uint2 vb = *(const uint2*)(Vc + vrow + ((4 * ks + 2 + gh) ^ qx) * 8 + gs);
            vv.d[0] = va.x; vv.d[1] = va.y; vv.d[2] = vb.x; vv.d[3] = vb.y;
            vfrag[ks] = vv.v;
        }
        // S^T = K·Q^T : lane holds keys (kj*16 + 4g..+3) of qrow (mi*16+qc)
        f32x4 s_[4][2];
        #pragma unroll
        for (int kj = 0; kj < 4; ++kj)
            #pragma unroll
            for (int mi = 0; mi < 2; ++mi) {
                f32x4 zz = {0.f, 0.f, 0.f, 0.f};
                s_[kj][mi] = __builtin_amdgcn_mfma_f32_16x16x32_bf16(
                    kf[kj], qf[mi], zz, 0, 0, 0);
            }
        // P = exp2(S), packed to bf16 pairs — stays in registers
        u32 dd[2][4][2];
        #pragma unroll
        for (int mi = 0; mi < 2; ++mi)
            #pragma unroll
            for (int kj = 0; kj < 4; ++kj) {
                f32x4 sv = s_[kj][mi];
                dd[mi][kj][0] = pack_bf(fexp2(sv[0]), fexp2(sv[1]));
                dd[mi][kj][1] = pack_bf(fexp2(sv[2]), fexp2(sv[3]));
            }
        // O += P V ; L += P @ ones (A-frag = own packed dwords, key order pi)
        #pragma unroll
        for (int ks = 0; ks < 2; ++ks)
            #pragma unroll
            for (int mi = 0; mi < 2; ++mi) {
                union { u32 d[4]; short8 v; } ap;
                ap.d[0] = dd[mi][2 * ks][0];     ap.d[1] = dd[mi][2 * ks][1];
                ap.d[2] = dd[mi][2 * ks + 1][0]; ap.d[3] = dd[mi][2 * ks + 1][1];
                o_[mi] = __builtin_amdgcn_mfma_f32_16x16x32_bf16(ap.v, vfrag[ks], o_[mi], 0, 0, 0);
                ls[mi] = __builtin_amdgcn_mfma_f32_16x16x32_bf16(ap.v, onesB, ls[mi], 0, 0, 0);
            }
    };

    // prologue: stage tiles 0,1 into buffer 0 slots 0,1
    gld16(Kg,        KsF + kband);
    gld16(Kg + 2048, KsF + 2048 + kband);
    if (w == 0) { gld16(Vg0,      VsF);        gld16(Vg0 + 64,  VsF + 1024); }
    if (w == 1) { gld16(Vg1,      VsF + 512);  gld16(Vg1 + 64,  VsF + 1536); }
    __syncthreads();

    // intervals: [tiles 0-1], then 10 x [3 tiles]  (2 + 30 = 32)
    for (int it = 0; it < 11; ++it) {
        const int cb = it & 1;
        if (it < 10) {
            const int nb = cb ^ 1;
            const int t0 = 2 + 3 * it;
            #pragma unroll
            for (int s = 0; s < 3; ++s) {
                const size_t ko = (size_t)(t0 + s) * 2048;   // K u16 offset
                const int    vo = (t0 + s) * 64;             // V u16 offset
                gld16(Kg + ko, KsF + nb * 6144 + s * 2048 + kband);
                if (w == 0) gld16(Vg0 + vo, VsF + nb * 3072 + s * 1024);
                if (w == 1) gld16(Vg1 + vo, VsF + nb * 3072 + s * 1024 + 512);
            }
        }
        compute_tile(KsF + cb * 6144,        VsF + cb * 3072);
        compute_tile(KsF + cb * 6144 + 2048, VsF + cb * 3072 + 1024);
        if (it > 0)
            compute_tile(KsF + cb * 6144 + 4096, VsF + cb * 3072 + 2048);
        __syncthreads();
    }

    // epilogue: O/L -> ctx bf16 (S*B, 128); per-wave complete, no merge
    const int b = bh >> 3, h = bh & 7;
    #pragma unroll
    for (int mi = 0; mi < 2; ++mi)
        #pragma unroll
        for (int r = 0; r < 4; ++r) {
            int qrow = q0 + w * 32 + mi * 16 + 4 * g + r;
            ctx[((size_t)qrow * BATCH + b) * DPROJ + h * DH + qc] =
                f2bf(o_[mi][r] / ls[mi][r]);
        }
}

// ---------------------------------------------------------------------------
extern "C" void kernel_launch(void* const* d_in, const int* in_sizes, int n_in,
                              void* d_out, int out_size, void* d_ws, size_t ws_size,
                              hipStream_t stream) {
    const float* src = (const float*)d_in[0];
    const float* Wq  = (const float*)d_in[1];
    const float* bq  = (const float*)d_in[2];
    const float* Wk  = (const float*)d_in[3];
    const float* bk  = (const float*)d_in[4];
    const float* Wv  = (const float*)d_in[5];
    const float* bv  = (const float*)d_in[6];
    const float* Wo  = (const float*)d_in[7];
    const float* g1  = (const float*)d_in[8];
    const float* be1 = (const float*)d_in[9];
    const float* W1  = (const float*)d_in[10];
    const float* b1  = (const float*)d_in[11];
    const float* W2  = (const float*)d_in[12];
    const float* b2  = (const float*)d_in[13];
    const float* g2  = (const float*)d_in[14];
    const float* be2 = (const float*)d_in[15];
    char* ws = (char*)d_ws;
    float* out = (float*)d_out;

    // liveness-packed workspace (bytes):
    u16* qhp  = (u16*)(ws + 0);          //  8 MB [bh][s][32]   dead after attn
    u16* khp  = (u16*)(ws + 8388608);    //  8 MB               dead after attn
    u16* vhb  = (u16*)(ws + 16777216);   //  4 MB [bh][s][16]   dead after transpose
    u16* vT   = (u16*)(ws + 20971520);   //  4 MB [bh][dh][2048] dead after attn
    u16* ctxb = (u16*)(ws + 25165824);   //  4 MB               dead after Wo
    u16* hb   = (u16*)(ws + 0);          // 32 MB  reuses all-dead 0..32M
    u16* xb   = (u16*)(ws + 37748736);   //  8 MB   live Wo+LN1 -> FFN2+LN2
    u16* srcb = (u16*)(ws + 54525952);   //  8 MB
    u16* WqT  = (u16*)(ws + 62914560);
    u16* WkT  = (u16*)(ws + 62980096);
    u16* WvT  = (u16*)(ws + 63045632);
    u16* WoT  = (u16*)(ws + 63111168);
    u16* W1T  = (u16*)(ws + 63176704);   // 512 KB
    u16* W2T  = (u16*)(ws + 63700992);   // 512 KB

    // 0) conversions (merged)
    prep_kernel<<<6656, 256, 0, stream>>>(src, srcb, Wq, Wk, Wv, Wo, W1, W2,
                                          WqT, WkT, WvT, WoT, W1T, W2T);
    // 1) QKV -> bf16 head layout (paired-K dbuf loop)
    qkv_mfma<<<dim3(128, 1, 3), 256, 0, stream>>>(srcb, WqT, WkT, WvT,
                                                  bq, bk, bv, qhp, khp, vhb);
    // 1b) V transpose
    transpose_v<<<dim3(16, 64), 256, 0, stream>>>(vhb, vT);
    // 2) MFMA flash attention, 3 tiles/barrier -> ctx bf16 (S*B, 128)
    attn_mfma<<<dim3(16, 64), 256, 0, stream>>>(qhp, khp, vT, ctxb);
    // 3+4) xb = bf16(LN1(src + ctx @ Wo)) — fused, paired-K, 512 blocks
    gemm_ln<false, true, true><<<512, 256, 0, stream>>>(
        ctxb, WoT, nullptr, src, g1, be1, xb, DPROJ);
    // 5) hb = relu(xb @ W1 + b1) (bf16), 128x128 tiles -> 1024 blocks
    mfma_gemm<128, 128, true, true, true><<<dim3(128, 8), 256, 0, stream>>>(
        xb, W1T, b1, hb, MROWS, DFF, DMODEL);
    // 6+7) out = LN2(xb + hb @ W2 + b2) fp32 — fused, paired-K, 512 blocks
    gemm_ln<true, false, false><<<512, 256, 0, stream>>>(
        hb, W2T, b2, xb, g2, be2, out, DFF);
}

// Round 14
// 202.951 us; speedup vs baseline: 1.0069x; 1.0069x over previous
//
#include <hip/hip_runtime.h>
#include <math.h>

#define SLEN 2048
#define BATCH 8
#define DMODEL 256
#define HEADS 8
#define DPROJ 128
#define DFF 1024
#define DH 16
#define MROWS (SLEN*BATCH)   // 16384

typedef unsigned short u16;
typedef unsigned int u32;
typedef __attribute__((ext_vector_type(8))) short short8;
typedef __attribute__((ext_vector_type(4))) float f32x4;
typedef __attribute__((ext_vector_type(4))) unsigned short u16x4;

__device__ __forceinline__ u16 f2bf(float x) {
    union { float f; u32 u; } v; v.f = x;
    u32 r = v.u + 0x7FFFu + ((v.u >> 16) & 1u);
    return (u16)(r >> 16);
}
__device__ __forceinline__ float bf2f(u16 h) {
    union { u32 u; float f; } v; v.u = ((u32)h) << 16;
    return v.f;
}
__device__ __forceinline__ float fexp2(float x) { return __builtin_amdgcn_exp2f(x); }
// pack bf16(lo),bf16(hi) (truncating) into one dword via v_perm_b32; the
// truncation bias cancels in O/L since L is computed from the same truncated P
__device__ __forceinline__ u32 pack_bf(float lo, float hi) {
    union { float f; u32 u; } a, b; a.f = lo; b.f = hi;
    return __builtin_amdgcn_perm(b.u, a.u, 0x07060302u);
}
// async global->LDS 16B: per-lane global addr, wave-uniform LDS base
// (HW writes lds_base + lane*16)
__device__ __forceinline__ void gld16(const u16* g, u16* l) {
    __builtin_amdgcn_global_load_lds(
        (const __attribute__((address_space(1))) void*)g,
        (__attribute__((address_space(3))) void*)l, 16, 0, 0);
}

// ---------------------------------------------------------------------------
// prep: src fp32->bf16 (blocks 0..4095) + weight transpose+convert (rest)
// ---------------------------------------------------------------------------
__global__ void prep_kernel(const float* __restrict__ src, u16* __restrict__ srcb,
                            const float* __restrict__ Wq, const float* __restrict__ Wk,
                            const float* __restrict__ Wv, const float* __restrict__ Wo,
                            const float* __restrict__ W1, const float* __restrict__ W2,
                            u16* __restrict__ WqT, u16* __restrict__ WkT,
                            u16* __restrict__ WvT, u16* __restrict__ WoT,
                            u16* __restrict__ W1T, u16* __restrict__ W2T) {
    if (blockIdx.x < 4096) {
        int idx = (blockIdx.x * 256 + threadIdx.x) * 4;
        float4 v = *(const float4*)(src + idx);
        u16x4 o;
        o.x = f2bf(v.x); o.y = f2bf(v.y); o.z = f2bf(v.z); o.w = f2bf(v.w);
        *(u16x4*)(srcb + idx) = o;
        return;
    }
    int i = (blockIdx.x - 4096) * 256 + threadIdx.x;
    if (i < 32768) {                       // WqT [128][256]
        int n = i >> 8, k = i & 255;
        WqT[i] = f2bf(Wq[k * 128 + n]);
    } else if (i < 65536) {
        int j = i - 32768; int n = j >> 8, k = j & 255;
        WkT[j] = f2bf(Wk[k * 128 + n]);
    } else if (i < 98304) {
        int j = i - 65536; int n = j >> 8, k = j & 255;
        WvT[j] = f2bf(Wv[k * 128 + n]);
    } else if (i < 131072) {               // WoT [256][128]
        int j = i - 98304; int n = j >> 7, k = j & 127;
        WoT[j] = f2bf(Wo[k * 256 + n]);
    } else if (i < 393216) {               // W1T [1024][256]
        int j = i - 131072; int n = j >> 8, k = j & 255;
        W1T[j] = f2bf(W1[k * 1024 + n]);
    } else if (i < 655360) {               // W2T [256][1024]
        int j = i - 393216; int n = j >> 10, k = j & 1023;
        W2T[j] = f2bf(W2[k * 256 + n]);
    }
}

// ---------------------------------------------------------------------------
// bf16 MFMA GEMM v2 — double-buffered LDS, ONE barrier per 32-K step.
// (used for FFN1 — pairing K-steps here would halve its 4 blocks/CU
//  occupancy per the m132 regression, so it stays single.)
// ---------------------------------------------------------------------------
template<int BM, int BN, bool RELU, bool HAS_BIAS, bool OUT_BF16>
__global__ void mfma_gemm(const u16* __restrict__ A, const u16* __restrict__ BT,
                          const float* __restrict__ bias, void* __restrict__ Cout,
                          int M, int N, int K) {
    constexpr int MI = BM / 32;
    constexpr int NJ = BN / 32;
    __shared__ __align__(16) u16 As[2][BM * 32];
    __shared__ __align__(16) u16 Bs[2][BN * 32];
    const int tid = threadIdx.x;
    const int row0 = blockIdx.x * BM;
    const int col0 = blockIdx.y * BN;
    const int w = tid >> 6, l = tid & 63;
    const int wr = (w & 1) * (BM / 2), wc = (w >> 1) * (BN / 2);
    const int lcol = l & 15, lrow = (l >> 4) * 4, g = l >> 4;
    const int sl = l >> 2;                       // sub-row within 16-row band
    const int swc = ((l & 3) ^ (sl & 3)) * 8;    // swizzled global chunk (u16)
    const int fsw = (g ^ (lcol & 3)) * 8;        // fragment slot offset (u16)

    const u16* Ag0 = A + (size_t)(row0 + 16 * w + sl) * K + swc;
    const u16* Bg0 = BT + (size_t)(col0 + 16 * w + sl) * K + swc;
    const int lofs = (16 * w) * 32;              // wave's staging band (u16)

    f32x4 acc[MI][NJ] = {};
    // prologue: stage k=0 into buffer 0
    gld16(Ag0, As[0] + lofs);
    if (BM == 128) gld16(Ag0 + (size_t)64 * K, As[0] + lofs + 64 * 32);
    gld16(Bg0, Bs[0] + lofs);
    if (BN == 128) gld16(Bg0 + (size_t)64 * K, Bs[0] + lofs + 64 * 32);
    __syncthreads();

    int cur = 0;
    for (int k0 = 0; k0 < K; k0 += 32) {
        // stage next 32-K slice into the other buffer (lands at the barrier)
        if (k0 + 32 < K) {
            const int nb = cur ^ 1;
            gld16(Ag0 + k0 + 32, As[nb] + lofs);
            if (BM == 128) gld16(Ag0 + (size_t)64 * K + k0 + 32, As[nb] + lofs + 64 * 32);
            gld16(Bg0 + k0 + 32, Bs[nb] + lofs);
            if (BN == 128) gld16(Bg0 + (size_t)64 * K + k0 + 32, Bs[nb] + lofs + 64 * 32);
        }
        short8 af[MI], bf[NJ];
        #pragma unroll
        for (int i = 0; i < MI; ++i)
            af[i] = *(const short8*)(As[cur] + (wr + i * 16 + lcol) * 32 + fsw);
        #pragma unroll
        for (int j = 0; j < NJ; ++j)
            bf[j] = *(const short8*)(Bs[cur] + (wc + j * 16 + lcol) * 32 + fsw);
        #pragma unroll
        for (int i = 0; i < MI; ++i)
            #pragma unroll
            for (int j = 0; j < NJ; ++j)
                acc[i][j] = __builtin_amdgcn_mfma_f32_16x16x32_bf16(
                    af[i], bf[j], acc[i][j], 0, 0, 0);
        __syncthreads();
        cur ^= 1;
    }
    float bv[NJ];
    #pragma unroll
    for (int j = 0; j < NJ; ++j)
        bv[j] = HAS_BIAS ? bias[col0 + wc + j * 16 + lcol] : 0.f;
    #pragma unroll
    for (int i = 0; i < MI; ++i) {
        #pragma unroll
        for (int r = 0; r < 4; ++r) {
            size_t grow = row0 + wr + i * 16 + lrow + r;
            #pragma unroll
            for (int j = 0; j < NJ; ++j) {
                int gcol = col0 + wc + j * 16 + lcol;
                float c = acc[i][j][r] + bv[j];
                if (RELU) c = fmaxf(c, 0.f);
                if (OUT_BF16) ((u16*)Cout)[grow * N + gcol] = f2bf(c);
                else          ((float*)Cout)[grow * N + gcol] = c;
            }
        }
    }
}

// ---------------------------------------------------------------------------
// Fused GEMM + residual-add + LayerNorm, TWO 32-K slices per barrier
// interval. Grid 512 = 2 blocks/CU is grid-limited, so the 72.5 KB LDS
// costs no occupancy. Wo: 4->2 intervals; FFN2: 32->16.
// Full-width tile 32 x 256; in-block LN via 16-lane butterfly + 512B LDS.
// ---------------------------------------------------------------------------
template<bool HAS_BIAS, bool RESID_F32, bool OUT_BF16>
__global__ void gemm_ln(const u16* __restrict__ A, const u16* __restrict__ BT,
                        const float* __restrict__ bias,
                        const void* __restrict__ resid,
                        const float* __restrict__ lng, const float* __restrict__ lnb,
                        void* __restrict__ Cout, int K) {
    __shared__ __align__(16) u16 As[2][2][32 * 32];   //  8 KB [buf][slice]
    __shared__ __align__(16) u16 Bs[2][2][256 * 32];  // 64 KB
    __shared__ float Ls[2][32][2];                    // 512 B
    const int tid = threadIdx.x;
    const int row0 = blockIdx.x * 32;
    const int w = tid >> 6, l = tid & 63;
    const int wr = (w & 1) * 16, wc = (w >> 1) * 128;
    const int lcol = l & 15, lrow = (l >> 4) * 4, g = l >> 4;
    const int sl = l >> 2;
    const int swc = ((l & 3) ^ (sl & 3)) * 8;
    const int fsw = (g ^ (lcol & 3)) * 8;

    u16* AsF = (u16*)As;   // buf stride 2048 u16, slice stride 1024
    u16* BsF = (u16*)Bs;   // buf stride 16384 u16, slice stride 8192

    // A staging: waves 0,1 stage 16-row band (w&1); waves 2,3 skip A
    const u16* Ag = A + (size_t)(row0 + 16 * (w & 1) + sl) * K + swc;
    const int lA0 = (16 * (w & 1)) * 32;
    // B staging: wave w stages bands w, w+4, w+8, w+12 (4 x 1KB per slice)
    const u16* Bg[4];
    int lB0[4];
    #pragma unroll
    for (int t = 0; t < 4; ++t) {
        Bg[t] = BT + (size_t)(16 * (w + 4 * t) + sl) * K + swc;
        lB0[t] = (16 * (w + 4 * t)) * 32;
    }

    f32x4 acc[8] = {};
    // prologue: stage interval 0 (slices k=0, k=32) into buffer 0
    if (w < 2) { gld16(Ag, AsF + lA0); gld16(Ag + 32, AsF + 1024 + lA0); }
    #pragma unroll
    for (int t = 0; t < 4; ++t) {
        gld16(Bg[t], BsF + lB0[t]);
        gld16(Bg[t] + 32, BsF + 8192 + lB0[t]);
    }
    __syncthreads();

    int cur = 0;
    for (int k0 = 0; k0 < K; k0 += 64) {
        // stage next interval (both slices) into the other buffer
        if (k0 + 64 < K) {
            const int nb = cur ^ 1;
            const int kn = k0 + 64;
            if (w < 2) {
                gld16(Ag + kn,      AsF + nb * 2048 + lA0);
                gld16(Ag + kn + 32, AsF + nb * 2048 + 1024 + lA0);
            }
            #pragma unroll
            for (int t = 0; t < 4; ++t) {
                gld16(Bg[t] + kn,      BsF + nb * 16384 + lB0[t]);
                gld16(Bg[t] + kn + 32, BsF + nb * 16384 + 8192 + lB0[t]);
            }
        }
        #pragma unroll
        for (int s2 = 0; s2 < 2; ++s2) {
            const u16* Ac = AsF + cur * 2048 + s2 * 1024;
            const u16* Bc = BsF + cur * 16384 + s2 * 8192;
            short8 af = *(const short8*)(Ac + (wr + lcol) * 32 + fsw);
            short8 bf[8];
            #pragma unroll
            for (int j = 0; j < 8; ++j)
                bf[j] = *(const short8*)(Bc + (wc + j * 16 + lcol) * 32 + fsw);
            #pragma unroll
            for (int j = 0; j < 8; ++j)
                acc[j] = __builtin_amdgcn_mfma_f32_16x16x32_bf16(af, bf[j], acc[j], 0, 0, 0);
        }
        __syncthreads();
        cur ^= 1;
    }

    // epilogue: e = acc + bias + resid  (acc[j][r] -> row wr+lrow+r, col wc+j*16+lcol)
    #pragma unroll
    for (int j = 0; j < 8; ++j) {
        const int col = wc + j * 16 + lcol;
        const float bv = HAS_BIAS ? bias[col] : 0.f;
        #pragma unroll
        for (int r = 0; r < 4; ++r) {
            const size_t row = (size_t)row0 + wr + lrow + r;
            float rv;
            if (RESID_F32) rv = ((const float*)resid)[row * 256 + col];
            else           rv = bf2f(((const u16*)resid)[row * 256 + col]);
            acc[j][r] += bv + rv;
        }
    }
    // per-row partials over this thread's 8 cols
    float s[4] = {0.f, 0.f, 0.f, 0.f}, q[4] = {0.f, 0.f, 0.f, 0.f};
    #pragma unroll
    for (int j = 0; j < 8; ++j)
        #pragma unroll
        for (int r = 0; r < 4; ++r) { s[r] += acc[j][r]; q[r] += acc[j][r] * acc[j][r]; }
    // butterfly over the 16-lane group sharing these rows (covers wave's 128 cols)
    #pragma unroll
    for (int off = 1; off < 16; off <<= 1)
        #pragma unroll
        for (int r = 0; r < 4; ++r) { s[r] += __shfl_xor(s[r], off); q[r] += __shfl_xor(q[r], off); }
    if (lcol == 0)
        #pragma unroll
        for (int r = 0; r < 4; ++r) {
            Ls[w >> 1][wr + lrow + r][0] = s[r];
            Ls[w >> 1][wr + lrow + r][1] = q[r];
        }
    __syncthreads();
    float mu[4], rs[4];
    #pragma unroll
    for (int r = 0; r < 4; ++r) {
        const int row = wr + lrow + r;
        const float fs = Ls[0][row][0] + Ls[1][row][0];
        const float fq = Ls[0][row][1] + Ls[1][row][1];
        mu[r] = fs * (1.0f / 256.0f);
        const float var = fq * (1.0f / 256.0f) - mu[r] * mu[r];
        rs[r] = rsqrtf(var + 1e-5f);
    }
    #pragma unroll
    for (int j = 0; j < 8; ++j) {
        const int col = wc + j * 16 + lcol;
        const float gv = lng[col], b2v = lnb[col];
        #pragma unroll
        for (int r = 0; r < 4; ++r) {
            const size_t row = (size_t)row0 + wr + lrow + r;
            const float o = (acc[j][r] - mu[r]) * rs[r] * gv + b2v;
            if (OUT_BF16) ((u16*)Cout)[row * 256 + col] = f2bf(o);
            else          ((float*)Cout)[row * 256 + col] = o;
        }
    }
}

// ---------------------------------------------------------------------------
// QKV MFMA GEMM v4 — TWO 32-K slices per barrier interval (8 -> 4
// intervals). Grid 384 = 1.5 blocks/CU is grid-limited, so the 64 KB LDS
// costs no occupancy. Outputs (coalesced vector stores):
//   q -> qhp [bh][s][32], scaled 0.25*log2e, dh 16..31 zero
//   k -> khp [bh][s][32], dh 16..31 zero
//   v -> vhb [bh][s][16]   (transposed by the separate transpose_v kernel —
//        round 10 measured the fused scatter at +7.5us, so it stays split)
// ---------------------------------------------------------------------------
__global__ void qkv_mfma(const u16* __restrict__ A,
                         const u16* __restrict__ WqT, const u16* __restrict__ WkT,
                         const u16* __restrict__ WvT,
                         const float* __restrict__ bq, const float* __restrict__ bk,
                         const float* __restrict__ bv,
                         u16* __restrict__ qhp, u16* __restrict__ khp,
                         u16* __restrict__ vhb) {
    const int which = blockIdx.z;
    const u16* BT   = which == 0 ? WqT : (which == 1 ? WkT : WvT);
    const float* bs = which == 0 ? bq : (which == 1 ? bk : bv);
    const float scale = which == 0 ? 0.25f * 1.44269504f : 1.0f;
    __shared__ __align__(16) u16 As[2][2][128 * 32];  // 32 KB [buf][slice]
    __shared__ __align__(16) u16 Bs[2][2][128 * 32];  // 32 KB
    const int tid = threadIdx.x;
    const int row0 = blockIdx.x * 128;
    const int w = tid >> 6, l = tid & 63;
    const int wr = (w & 1) * 64, wc = (w >> 1) * 64;
    const int lcol = l & 15, lrow = (l >> 4) * 4, g = l >> 4;
    const int sl = l >> 2;
    const int swc = ((l & 3) ^ (sl & 3)) * 8;
    const int fsw = (g ^ (lcol & 3)) * 8;

    u16* AsF = (u16*)As;   // buf stride 8192 u16, slice stride 4096
    u16* BsF = (u16*)Bs;
    const u16* Ag0 = A + (size_t)(row0 + 16 * w + sl) * DMODEL + swc;
    const u16* Bg0 = BT + (size_t)(16 * w + sl) * DMODEL + swc;
    const int lofs = (16 * w) * 32;

    f32x4 acc[4][4] = {};
    // prologue: stage interval 0 (slices k=0, k=32) into buffer 0
    gld16(Ag0,                       AsF + lofs);
    gld16(Ag0 + (size_t)64 * DMODEL, AsF + lofs + 2048);
    gld16(Ag0 + 32,                       AsF + 4096 + lofs);
    gld16(Ag0 + (size_t)64 * DMODEL + 32, AsF + 4096 + lofs + 2048);
    gld16(Bg0,                       BsF + lofs);
    gld16(Bg0 + (size_t)64 * DMODEL, BsF + lofs + 2048);
    gld16(Bg0 + 32,                       BsF + 4096 + lofs);
    gld16(Bg0 + (size_t)64 * DMODEL + 32, BsF + 4096 + lofs + 2048);
    __syncthreads();

    int cur = 0;
    for (int k0 = 0; k0 < DMODEL; k0 += 64) {
        if (k0 + 64 < DMODEL) {
            const int nb = cur ^ 1;
            const int kn = k0 + 64;
            gld16(Ag0 + kn,                       AsF + nb * 8192 + lofs);
            gld16(Ag0 + (size_t)64 * DMODEL + kn, AsF + nb * 8192 + lofs + 2048);
            gld16(Ag0 + kn + 32,                       AsF + nb * 8192 + 4096 + lofs);
            gld16(Ag0 + (size_t)64 * DMODEL + kn + 32, AsF + nb * 8192 + 4096 + lofs + 2048);
            gld16(Bg0 + kn,                       BsF + nb * 8192 + lofs);
            gld16(Bg0 + (size_t)64 * DMODEL + kn, BsF + nb * 8192 + lofs + 2048);
            gld16(Bg0 + kn + 32,                       BsF + nb * 8192 + 4096 + lofs);
            gld16(Bg0 + (size_t)64 * DMODEL + kn + 32, BsF + nb * 8192 + 4096 + lofs + 2048);
        }
        #pragma unroll
        for (int s2 = 0; s2 < 2; ++s2) {
            const u16* Ac = AsF + cur * 8192 + s2 * 4096;
            const u16* Bc = BsF + cur * 8192 + s2 * 4096;
            short8 af[4], bf[4];
            #pragma unroll
            for (int i = 0; i < 4; ++i)
                af[i] = *(const short8*)(Ac + (wr + i * 16 + lcol) * 32 + fsw);
            #pragma unroll
            for (int j = 0; j < 4; ++j)
                bf[j] = *(const short8*)(Bc + (wc + j * 16 + lcol) * 32 + fsw);
            #pragma unroll
            for (int i = 0; i < 4; ++i)
                #pragma unroll
                for (int j = 0; j < 4; ++j)
                    acc[i][j] = __builtin_amdgcn_mfma_f32_16x16x32_bf16(
                        af[i], bf[j], acc[i][j], 0, 0, 0);
        }
        __syncthreads();
        cur ^= 1;
    }
    #pragma unroll
    for (int i = 0; i < 4; ++i) {
        #pragma unroll
        for (int r = 0; r < 4; ++r) {
            int grow = row0 + wr + i * 16 + lrow + r;
            int b = grow & 7, s = grow >> 3;
            #pragma unroll
            for (int j = 0; j < 4; ++j) {
                int gcol = wc + j * 16 + lcol;
                int h = gcol >> 4, d = gcol & 15;
                float c = acc[i][j][r] + bs[gcol];
                if (which == 2) {
                    vhb[((size_t)(b * 8 + h) * SLEN + s) * 16 + d] = f2bf(c);
                } else {
                    u16* base = (which == 0 ? qhp : khp)
                              + ((size_t)(b * 8 + h) * SLEN + s) * 32;
                    base[d] = f2bf(c * scale);
                    base[d + 16] = 0;
                }
            }
        }
    }
}

// ---------------------------------------------------------------------------
// V transpose: vhb [bh][s][16] -> vT [bh][dh][2048]
// ---------------------------------------------------------------------------
__global__ void transpose_v(const u16* __restrict__ vhb, u16* __restrict__ vT) {
    __shared__ u16 T[128 * 24];
    const int bh = blockIdx.y;
    const int c0 = blockIdx.x * 128;
    const int t = threadIdx.x;
    {
        int key = t >> 1, half = t & 1;
        *(uint4*)(T + key * 24 + half * 8) =
            *(const uint4*)(vhb + ((size_t)bh * SLEN + c0 + key) * 16 + half * 8);
    }
    __syncthreads();
    int d = t >> 4, k8 = (t & 15) * 8;
    u16x4 o0, o1;
    o0.x = T[(k8 + 0) * 24 + d]; o0.y = T[(k8 + 1) * 24 + d];
    o0.z = T[(k8 + 2) * 24 + d]; o0.w = T[(k8 + 3) * 24 + d];
    o1.x = T[(k8 + 4) * 24 + d]; o1.y = T[(k8 + 5) * 24 + d];
    o1.z = T[(k8 + 6) * 24 + d]; o1.w = T[(k8 + 7) * 24 + d];
    u16* dst = vT + ((size_t)bh * 16 + d) * SLEN + c0 + k8;
    *(u16x4*)dst = o0;
    *(u16x4*)(dst + 4) = o1;
}

// ---------------------------------------------------------------------------
// MFMA flash attention v10 — v8 body, TWO 64-key tiles per barrier interval.
// (best measured: 45.5-46.1 us; 3-tile intervals measured neutral in r13,
// so this stays 2-tile. Remaining stall is the intra-tile dependency chain
// ds_read -> S-MFMA -> exp2 x32 -> pack -> PV; breaking it needs an
// instruction-level counted-vmcnt/setprio schedule, out of scope here.)
// ---------------------------------------------------------------------------
__global__ __launch_bounds__(256, 4)
void attn_mfma(const u16* __restrict__ qg, const u16* __restrict__ kg,
               const u16* __restrict__ vT, u16* __restrict__ ctx) {
    __shared__ __align__(16) u16 Ks[2][2][64 * 32];   // 16384 B [buf][tile]
    __shared__ __align__(16) u16 Vs[2][2][16 * 64];   //  8192 B [buf][tile]
    const int bh = blockIdx.y;
    const int q0 = blockIdx.x * 128;
    const int tid = threadIdx.x;
    const int w = tid >> 6, l = tid & 63;
    const int qc = l & 15, g = l >> 4;

    // Q fragments: 32 rows per wave, loaded once
    short8 qf[2];
    {
        const u16* qbase = qg + ((size_t)bh * SLEN + q0 + w * 32) * 32;
        qf[0] = *(const short8*)(qbase + qc * 32 + 8 * g);
        qf[1] = *(const short8*)(qbase + (16 + qc) * 32 + 8 * g);
    }

    // K staging: wave w stages 16-row band w of each 64-key tile.
    const int sl = l >> 2;
    const int swc = ((l & 3) ^ (sl & 3)) * 8;
    const u16* Kg = kg + (size_t)bh * SLEN * 32 + (size_t)(16 * w + sl) * 32 + swc;
    u16* KsF = (u16*)Ks;                 // buf stride 4096 u16, tile stride 2048
    u16* lK = KsF + (16 * w) * 32;
    // V staging: tile = 16 dh-rows x 64 keys (128B/row); w==0 stages rows 0-7,
    // w==1 rows 8-15; chunk slot c holds global chunk c^(row&7).
    const int vr = l >> 3, vc = l & 7;
    const int vsw0 = (vc ^ (vr & 7)) * 8;
    const u16* Vg0 = vT + ((size_t)bh * 16 + vr) * SLEN + vsw0;      // rows 0-7
    const u16* Vg1 = vT + ((size_t)bh * 16 + 8 + vr) * SLEN + vsw0;  // rows 8-15
    u16* VsF = (u16*)Vs;                 // buf stride 2048 u16, tile stride 1024
    // fragment offsets
    const int fsw = (g ^ (qc & 3)) * 8;            // K: [row][32] pattern
    const int qx = qc & 7, gh = g >> 1, gs = (g & 1) * 4;
    const int vrow = qc * 64;                      // V row base (u16)

    f32x4 o_[2] = {};
    f32x4 ls[2] = {};
    const short one_bf = (short)0x3F80;
    short8 onesB = {one_bf, one_bf, one_bf, one_bf, one_bf, one_bf, one_bf, one_bf};

    // one-tile compute body (register-P, permuted-key V fragments)
    auto compute_tile = [&](const u16* Kc, const u16* Vc) {
        short8 kf[4];
        #pragma unroll
        for (int kj = 0; kj < 4; ++kj)
            kf[kj] = *(const short8*)(Kc + (kj * 16 + qc) * 32 + fsw);
        short8 vfrag[2];
        #pragma unroll
        for (int ks = 0; ks < 2; ++ks) {
            union { u32 d[4]; short8 v; } vv;
            uint2 va = *(const uint2*)(Vc + vrow + ((4 * ks + gh) ^ qx) * 8 + gs);
            uint2 vb = *(const uint2*)(Vc + vrow + ((4 * ks + 2 + gh) ^ qx) * 8 + gs);
            vv.d[0] = va.x; vv.d[1] = va.y; vv.d[2] = vb.x; vv.d[3] = vb.y;
            vfrag[ks] = vv.v;
        }
        // S^T = K·Q^T : lane holds keys (kj*16 + 4g..+3) of qrow (mi*16+qc)
        f32x4 s_[4][2];
        #pragma unroll
        for (int kj = 0; kj < 4; ++kj)
            #pragma unroll
            for (int mi = 0; mi < 2; ++mi) {
                f32x4 zz = {0.f, 0.f, 0.f, 0.f};
                s_[kj][mi] = __builtin_amdgcn_mfma_f32_16x16x32_bf16(
                    kf[kj], qf[mi], zz, 0, 0, 0);
            }
        // P = exp2(S), packed to bf16 pairs — stays in registers
        u32 dd[2][4][2];
        #pragma unroll
        for (int mi = 0; mi < 2; ++mi)
            #pragma unroll
            for (int kj = 0; kj < 4; ++kj) {
                f32x4 sv = s_[kj][mi];
                dd[mi][kj][0] = pack_bf(fexp2(sv[0]), fexp2(sv[1]));
                dd[mi][kj][1] = pack_bf(fexp2(sv[2]), fexp2(sv[3]));
            }
        // O += P V ; L += P @ ones (A-frag = own packed dwords, key order pi)
        #pragma unroll
        for (int ks = 0; ks < 2; ++ks)
            #pragma unroll
            for (int mi = 0; mi < 2; ++mi) {
                union { u32 d[4]; short8 v; } ap;
                ap.d[0] = dd[mi][2 * ks][0];     ap.d[1] = dd[mi][2 * ks][1];
                ap.d[2] = dd[mi][2 * ks + 1][0]; ap.d[3] = dd[mi][2 * ks + 1][1];
                o_[mi] = __builtin_amdgcn_mfma_f32_16x16x32_bf16(ap.v, vfrag[ks], o_[mi], 0, 0, 0);
                ls[mi] = __builtin_amdgcn_mfma_f32_16x16x32_bf16(ap.v, onesB, ls[mi], 0, 0, 0);
            }
    };

    // prologue: stage pair 0 (tiles 0,1) into buffer 0
    gld16(Kg,                 lK);
    gld16(Kg + 2048,          lK + 2048);
    if (w == 0) { gld16(Vg0,      VsF);        gld16(Vg0 + 64,  VsF + 1024); }
    if (w == 1) { gld16(Vg1,      VsF + 512);  gld16(Vg1 + 64,  VsF + 1536); }
    __syncthreads();

    int cur = 0;
    for (int pt = 0; pt < 16; ++pt) {
        // stage next pair into the other buffer (completes at the barrier)
        if (pt + 1 < 16) {
            const size_t ko = (size_t)(pt + 1) * 2 * 2048;   // K u16 offset
            const int    vo = (pt + 1) * 128;                // V u16 offset
            const int nb = cur ^ 1;
            gld16(Kg + ko,        KsF + nb * 4096 + (16 * w) * 32);
            gld16(Kg + ko + 2048, KsF + nb * 4096 + 2048 + (16 * w) * 32);
            if (w == 0) {
                gld16(Vg0 + vo,      VsF + nb * 2048);
                gld16(Vg0 + vo + 64, VsF + nb * 2048 + 1024);
            }
            if (w == 1) {
                gld16(Vg1 + vo,      VsF + nb * 2048 + 512);
                gld16(Vg1 + vo + 64, VsF + nb * 2048 + 1536);
            }
        }
        compute_tile(KsF + cur * 4096,        VsF + cur * 2048);
        compute_tile(KsF + cur * 4096 + 2048, VsF + cur * 2048 + 1024);
        __syncthreads();
        cur ^= 1;
    }

    // epilogue: O/L -> ctx bf16 (S*B, 128); per-wave complete, no merge
    const int b = bh >> 3, h = bh & 7;
    #pragma unroll
    for (int mi = 0; mi < 2; ++mi)
        #pragma unroll
        for (int r = 0; r < 4; ++r) {
            int qrow = q0 + w * 32 + mi * 16 + 4 * g + r;
            ctx[((size_t)qrow * BATCH + b) * DPROJ + h * DH + qc] =
                f2bf(o_[mi][r] / ls[mi][r]);
        }
}

// ---------------------------------------------------------------------------
extern "C" void kernel_launch(void* const* d_in, const int* in_sizes, int n_in,
                              void* d_out, int out_size, void* d_ws, size_t ws_size,
                              hipStream_t stream) {
    const float* src = (const float*)d_in[0];
    const float* Wq  = (const float*)d_in[1];
    const float* bq  = (const float*)d_in[2];
    const float* Wk  = (const float*)d_in[3];
    const float* bk  = (const float*)d_in[4];
    const float* Wv  = (const float*)d_in[5];
    const float* bv  = (const float*)d_in[6];
    const float* Wo  = (const float*)d_in[7];
    const float* g1  = (const float*)d_in[8];
    const float* be1 = (const float*)d_in[9];
    const float* W1  = (const float*)d_in[10];
    const float* b1  = (const float*)d_in[11];
    const float* W2  = (const float*)d_in[12];
    const float* b2  = (const float*)d_in[13];
    const float* g2  = (const float*)d_in[14];
    const float* be2 = (const float*)d_in[15];
    char* ws = (char*)d_ws;
    float* out = (float*)d_out;

    // liveness-packed workspace (bytes):
    u16* qhp  = (u16*)(ws + 0);          //  8 MB [bh][s][32]   dead after attn
    u16* khp  = (u16*)(ws + 8388608);    //  8 MB               dead after attn
    u16* vhb  = (u16*)(ws + 16777216);   //  4 MB [bh][s][16]   dead after transpose
    u16* vT   = (u16*)(ws + 20971520);   //  4 MB [bh][dh][2048] dead after attn
    u16* ctxb = (u16*)(ws + 25165824);   //  4 MB               dead after Wo
    u16* hb   = (u16*)(ws + 0);          // 32 MB  reuses all-dead 0..32M
    u16* xb   = (u16*)(ws + 37748736);   //  8 MB   live Wo+LN1 -> FFN2+LN2
    u16* srcb = (u16*)(ws + 54525952);   //  8 MB
    u16* WqT  = (u16*)(ws + 62914560);
    u16* WkT  = (u16*)(ws + 62980096);
    u16* WvT  = (u16*)(ws + 63045632);
    u16* WoT  = (u16*)(ws + 63111168);
    u16* W1T  = (u16*)(ws + 63176704);   // 512 KB
    u16* W2T  = (u16*)(ws + 63700992);   // 512 KB

    // 0) conversions (merged)
    prep_kernel<<<6656, 256, 0, stream>>>(src, srcb, Wq, Wk, Wv, Wo, W1, W2,
                                          WqT, WkT, WvT, WoT, W1T, W2T);
    // 1) QKV -> bf16 head layout (paired-K dbuf loop)
    qkv_mfma<<<dim3(128, 1, 3), 256, 0, stream>>>(srcb, WqT, WkT, WvT,
                                                  bq, bk, bv, qhp, khp, vhb);
    // 1b) V transpose
    transpose_v<<<dim3(16, 64), 256, 0, stream>>>(vhb, vT);
    // 2) MFMA flash attention, 2 tiles/barrier -> ctx bf16 (S*B, 128)
    attn_mfma<<<dim3(16, 64), 256, 0, stream>>>(qhp, khp, vT, ctxb);
    // 3+4) xb = bf16(LN1(src + ctx @ Wo)) — fused, paired-K, 512 blocks
    gemm_ln<false, true, true><<<512, 256, 0, stream>>>(
        ctxb, WoT, nullptr, src, g1, be1, xb, DPROJ);
    // 5) hb = relu(xb @ W1 + b1) (bf16), 128x128 tiles -> 1024 blocks
    mfma_gemm<128, 128, true, true, true><<<dim3(128, 8), 256, 0, stream>>>(
        xb, W1T, b1, hb, MROWS, DFF, DMODEL);
    // 6+7) out = LN2(xb + hb @ W2 + b2) fp32 — fused, paired-K, 512 blocks
    gemm_ln<true, false, false><<<512, 256, 0, stream>>>(
        hb, W2T, b2, xb, g2, be2, out, DFF);
}